// Round 18
// baseline (84.231 us; speedup 1.0000x reference)
//
#include <hip/hip_runtime.h>
#include <math.h>

#define BB 4
#define SS 4096
#define DK 5
#define TK 1024
#define NT 256
// (1/sqrt(5)) * log2(e) folded into a' so p = v_exp_f32(score)
#define LAM (0.44721359549995793f * 1.4426950408889634f)

typedef float v2f __attribute__((ext_vector_type(2)));

__device__ __forceinline__ float fast_exp2(float x) {
#if __has_builtin(__builtin_amdgcn_exp2f)
    return __builtin_amdgcn_exp2f(x);
#else
    float r; asm("v_exp_f32 %0, %1" : "=v"(r) : "v"(x)); return r;
#endif
}

// Packed fp32: compiler selects v_pk_fma_f32 on gfx90a+ for <2 x float> fma.
__device__ __forceinline__ v2f pk_fma(v2f a, v2f b, v2f c) {
    return __builtin_elementwise_fma(a, b, c);
}

// async global->LDS, 16B per lane (dest lane-contiguous)
#define GLOAD16(gp, lp)                                                        \
    __builtin_amdgcn_global_load_lds(                                          \
        (const __attribute__((address_space(1))) unsigned int*)(gp),           \
        (__attribute__((address_space(3))) unsigned int*)(lp), 16, 0, 0)

// ---------------------------------------------------------------------------
// Occupancy-doubled variant of R17 (best: 23.7 µs). m69: waves/CU halve at
// VGPR {64,128,256} -> R17's ~128 VGPR pinned us at 16 waves/CU while the
// kernel is ~4x stall-bound. This version: 2 ROWS/WAVE (one low row + its
// mirror high row -> per-wave work constant everywhere: each chunk ~1
// accumulating row + 1 denominator-only row), acc[2][4]+a'[2][3] ~ 60 VGPR,
// __launch_bounds__(256,8) targets VGPR<=64 => 32 waves/CU (8/SIMD), 2x TLP.
// 2048 blocks x 8 rows, TK=1024 AoS tiles (12 KB LDS, 8 blocks/CU).
//   score_rk = a'_r·x_k,  a'_r = LAM*(M^T x_r + Wk^T bq),  M = Wq^T Wk
//   acc_r = {Σ_past p·x, Σ_past p},  l_r = Σ_all p   (V folded out)
//   out_r,d = (Wv[d]·acc_x + bv[d]·acc_p)/l_r
// ---------------------------------------------------------------------------
__global__ __launch_bounds__(NT, 8) void attn(
    const float* __restrict__ x,
    const float* __restrict__ Wq, const float* __restrict__ bq,
    const float* __restrict__ Wk,
    const float* __restrict__ Wv, const float* __restrict__ bv,
    float* __restrict__ out)
{
    __shared__ float kls[3 * TK];          // AoS: key k at [k*3 .. k*3+2]

    const int tid = threadIdx.x;
    const int sub = tid & 63;
    const int wave = tid >> 6;

    const int b = blockIdx.x >> 9;         // 512 blocks per batch
    const int j = blockIdx.x & 511;
    const int rlo = j * 4 + wave;          // [0, 2048)
    const int rhi = (4092 - j * 4) + wave; // [2048, 4096)  (mirror quad)

    // M = Wq^T Wk (3x3) and u = Wk^T bq (uniform)
    float M00=0,M01=0,M02=0,M10=0,M11=0,M12=0,M20=0,M21=0,M22=0;
    float u0=0,u1=0,u2=0;
#pragma unroll
    for (int d = 0; d < DK; ++d) {
        float q0 = Wq[d*3+0], q1 = Wq[d*3+1], q2 = Wq[d*3+2];
        float k0 = Wk[d*3+0], k1 = Wk[d*3+1], k2 = Wk[d*3+2];
        float bqd = bq[d];
        M00 = fmaf(q0,k0,M00); M01 = fmaf(q0,k1,M01); M02 = fmaf(q0,k2,M02);
        M10 = fmaf(q1,k0,M10); M11 = fmaf(q1,k1,M11); M12 = fmaf(q1,k2,M12);
        M20 = fmaf(q2,k0,M20); M21 = fmaf(q2,k1,M21); M22 = fmaf(q2,k2,M22);
        u0 = fmaf(k0,bqd,u0);  u1 = fmaf(k1,bqd,u1);  u2 = fmaf(k2,bqd,u2);
    }

    const float* xb = x + (size_t)b * SS * 3;

    // per-row a' (broadcast into both packed halves); r=0 -> rlo, r=1 -> rhi
    v2f a2[2][3];
#pragma unroll
    for (int r = 0; r < 2; ++r) {
        const int row = r ? rhi : rlo;
        const float* xr = &xb[(size_t)row * 3];
        float x0 = xr[0], x1 = xr[1], x2 = xr[2];
        float av0 = LAM * (x0*M00 + x1*M10 + x2*M20 + u0);
        float av1 = LAM * (x0*M01 + x1*M11 + x2*M21 + u1);
        float av2 = LAM * (x0*M02 + x1*M12 + x2*M22 + u2);
        a2[r][0] = (v2f){av0, av0};
        a2[r][1] = (v2f){av1, av1};
        a2[r][2] = (v2f){av2, av2};
    }

    v2f l2[2];
    v2f acc2[2][4];              // {p*x0, p*x1, p*x2, p} over past keys
#pragma unroll
    for (int r = 0; r < 2; ++r) {
        l2[r] = (v2f){0.f, 0.f};
#pragma unroll
        for (int d = 0; d < 4; ++d) acc2[r][d] = (v2f){0.f, 0.f};
    }

    for (int t = 0; t < SS; t += TK) {     // 4 tiles
        __syncthreads();
        // stage AoS tile: 1024 keys x 3 floats = 768 float4 slots, linear
#pragma unroll
        for (int it = 0; it < 3; ++it) {
            int idx = it * NT + tid;
            GLOAD16(xb + (size_t)t * 3 + idx * 4, &kls[idx * 4]);
        }
        __syncthreads();

#pragma unroll
        for (int c = 0; c < TK / 256; ++c) {   // 4 chunks of 256 keys
            const int off    = (c * 256 + sub * 4) * 3;
            const int cstart = t + c * 256;     // wave-uniform chunk bounds
            const int cend   = cstart + 255;
            const int kbase  = cstart + sub * 4;

            float4 f0 = *(const float4*)&kls[off + 0];
            float4 f1 = *(const float4*)&kls[off + 4];
            float4 f2 = *(const float4*)&kls[off + 8];

#pragma unroll
            for (int h = 0; h < 2; ++h) {
                const int kgh = kbase + h * 2;
                v2f k0, k1, k2;
                if (h == 0) {
                    k0 = (v2f){f0.x, f0.w};
                    k1 = (v2f){f0.y, f1.x};
                    k2 = (v2f){f0.z, f1.y};
                } else {
                    k0 = (v2f){f1.z, f2.y};
                    k1 = (v2f){f1.w, f2.z};
                    k2 = (v2f){f2.x, f2.w};
                }
#pragma unroll
                for (int r = 0; r < 2; ++r) {
                    const int row = r ? rhi : rlo;
                    v2f sc = pk_fma(a2[r][0], k0,
                             pk_fma(a2[r][1], k1, a2[r][2] * k2));
                    v2f p;
                    p.x = fast_exp2(sc.x); p.y = fast_exp2(sc.y);
                    l2[r] += p;
                    if (cend <= row) {              // full accumulate
                        acc2[r][0] = pk_fma(p, k0, acc2[r][0]);
                        acc2[r][1] = pk_fma(p, k1, acc2[r][1]);
                        acc2[r][2] = pk_fma(p, k2, acc2[r][2]);
                        acc2[r][3] += p;
                    } else if (cstart <= row) {     // boundary: masked
                        v2f pm;
                        pm.x = (kgh + 0 <= row) ? p.x : 0.f;
                        pm.y = (kgh + 1 <= row) ? p.y : 0.f;
                        acc2[r][0] = pk_fma(pm, k0, acc2[r][0]);
                        acc2[r][1] = pk_fma(pm, k1, acc2[r][1]);
                        acc2[r][2] = pk_fma(pm, k2, acc2[r][2]);
                        acc2[r][3] += pm;
                    }
                    // else: future-only for this row -> denominator only
                }
            }
        }
    }

    // epilogue weights loaded only now (keeps them out of loop liveness)
    float wv0 = 0.f, wv1 = 0.f, wv2 = 0.f, bvl = 0.f;
    if (sub < DK) {
        wv0 = Wv[sub*3+0]; wv1 = Wv[sub*3+1]; wv2 = Wv[sub*3+2]; bvl = bv[sub];
    }

    // fold packed halves, butterfly-reduce 5 values across 64 lanes, project
#pragma unroll
    for (int r = 0; r < 2; ++r) {
        const int row = r ? rhi : rlo;
        float lr = l2[r].x + l2[r].y;
        float A0 = acc2[r][0].x + acc2[r][0].y;
        float A1 = acc2[r][1].x + acc2[r][1].y;
        float A2 = acc2[r][2].x + acc2[r][2].y;
        float PS = acc2[r][3].x + acc2[r][3].y;
#pragma unroll
        for (int off = 32; off >= 1; off >>= 1) {
            lr += __shfl_xor(lr, off);
            A0 += __shfl_xor(A0, off);
            A1 += __shfl_xor(A1, off);
            A2 += __shfl_xor(A2, off);
            PS += __shfl_xor(PS, off);
        }
        if (sub < DK) {
            float num = fmaf(wv0, A0, fmaf(wv1, A1, fmaf(wv2, A2, bvl * PS)));
            out[((size_t)b * SS + row) * DK + sub] = num / lr;
        }
    }
}

extern "C" void kernel_launch(void* const* d_in, const int* in_sizes, int n_in,
                              void* d_out, int out_size, void* d_ws, size_t ws_size,
                              hipStream_t stream) {
    const float* x  = (const float*)d_in[0];
    const float* Wq = (const float*)d_in[1];
    const float* bq = (const float*)d_in[2];
    const float* Wk = (const float*)d_in[3];
    const float* Wv = (const float*)d_in[5];
    const float* bv = (const float*)d_in[6];
    float* outp = (float*)d_out;

    attn<<<BB * 512, NT, 0, stream>>>(x, Wq, bq, Wk, Wv, bv, outp);
}

// Round 19
// 23.704 us; speedup vs baseline: 3.5535x; 3.5535x over previous
//
#include <hip/hip_runtime.h>
#include <math.h>

#define BB 4
#define SS 4096
#define DK 5
#define TK 2048
#define NT 256
// (1/sqrt(5)) * log2(e) folded into a' so p = v_exp_f32(score)
#define LAM (0.44721359549995793f * 1.4426950408889634f)

typedef float v2f __attribute__((ext_vector_type(2)));

__device__ __forceinline__ float fast_exp2(float x) {
#if __has_builtin(__builtin_amdgcn_exp2f)
    return __builtin_amdgcn_exp2f(x);
#else
    float r; asm("v_exp_f32 %0, %1" : "=v"(r) : "v"(x)); return r;
#endif
}

// Packed fp32: compiler selects v_pk_fma_f32 on gfx90a+ for <2 x float> fma.
__device__ __forceinline__ v2f pk_fma(v2f a, v2f b, v2f c) {
    return __builtin_elementwise_fma(a, b, c);
}

// async global->LDS, 16B per lane (dest lane-contiguous)
#define GLOAD16(gp, lp)                                                        \
    __builtin_amdgcn_global_load_lds(                                          \
        (const __attribute__((address_space(1))) unsigned int*)(gp),           \
        (__attribute__((address_space(3))) unsigned int*)(lp), 16, 0, 0)

// build the h-th packed key-pair slice from the 3 AoS float4s
#define K_SLICES(h)                                                            \
    v2f k0, k1, k2;                                                            \
    if ((h) == 0) {                                                            \
        k0 = (v2f){f0.x, f0.w};                                                \
        k1 = (v2f){f0.y, f1.x};                                                \
        k2 = (v2f){f0.z, f1.y};                                                \
    } else {                                                                   \
        k0 = (v2f){f1.z, f2.y};                                                \
        k1 = (v2f){f1.w, f2.z};                                                \
        k2 = (v2f){f2.x, f2.w};                                                \
    }

// ---------------------------------------------------------------------------
// R17 (best: 23.7 µs) + BALANCED row assignment, isolated A/B.
// Every wave owns {lo0, lo0+1} and the mirror {hi0, hi0+1}: all waves in a
// block do identical per-tile work -> no stranding at the mid-tile barrier.
// Unlike R8/R15 (balanced but b64 reads / V-staging confounds), this keeps
// R17's 3 x ds_read_b128 per chunk; only the 3-way gate runs twice (per
// pair). Liveness shape is R17's: per-pair branch regions contain the fused
// score->exp->l->acc (no p-arrays spanning branches — R6/R7 spill lesson);
// k-slices rebuilt per pair from f registers.
//   score_rk = a'_r·x_k,  a'_r = LAM*(M^T x_r + Wk^T bq),  M = Wq^T Wk
//   acc_r = {Σ_past p·x, Σ_past p},  l_r = Σ_all p   (V folded out)
//   out_r,d = (Wv[d]·acc_x + bv[d]·acc_p)/l_r
// ---------------------------------------------------------------------------
__global__ __launch_bounds__(NT, 4) void attn(
    const float* __restrict__ x,
    const float* __restrict__ Wq, const float* __restrict__ bq,
    const float* __restrict__ Wk,
    const float* __restrict__ Wv, const float* __restrict__ bv,
    float* __restrict__ out)
{
    __shared__ float kls[3 * TK];          // AoS: key k at [k*3 .. k*3+2]

    const int tid = threadIdx.x;
    const int sub = tid & 63;
    const int wave = tid >> 6;

    const int b = blockIdx.x >> 8;
    const int i = blockIdx.x & 255;
    const int lo0 = i * 8 + wave * 2;          // rows: lo0, lo0+1, hi0, hi0+1
    const int hi0 = (511 - i) * 8 + wave * 2;

    // M = Wq^T Wk (3x3) and u = Wk^T bq (uniform)
    float M00=0,M01=0,M02=0,M10=0,M11=0,M12=0,M20=0,M21=0,M22=0;
    float u0=0,u1=0,u2=0;
#pragma unroll
    for (int d = 0; d < DK; ++d) {
        float q0 = Wq[d*3+0], q1 = Wq[d*3+1], q2 = Wq[d*3+2];
        float k0 = Wk[d*3+0], k1 = Wk[d*3+1], k2 = Wk[d*3+2];
        float bqd = bq[d];
        M00 = fmaf(q0,k0,M00); M01 = fmaf(q0,k1,M01); M02 = fmaf(q0,k2,M02);
        M10 = fmaf(q1,k0,M10); M11 = fmaf(q1,k1,M11); M12 = fmaf(q1,k2,M12);
        M20 = fmaf(q2,k0,M20); M21 = fmaf(q2,k1,M21); M22 = fmaf(q2,k2,M22);
        u0 = fmaf(k0,bqd,u0);  u1 = fmaf(k1,bqd,u1);  u2 = fmaf(k2,bqd,u2);
    }

    const float* xb = x + (size_t)b * SS * 3;

    // per-row a' (broadcast into both packed halves); rows: 0,1 = lo pair,
    // 2,3 = hi pair
    v2f a2[4][3];
#pragma unroll
    for (int r = 0; r < 4; ++r) {
        const int row = (r < 2) ? (lo0 + r) : (hi0 + r - 2);
        const float* xr = &xb[(size_t)row * 3];
        float x0 = xr[0], x1 = xr[1], x2 = xr[2];
        float av0 = LAM * (x0*M00 + x1*M10 + x2*M20 + u0);
        float av1 = LAM * (x0*M01 + x1*M11 + x2*M21 + u1);
        float av2 = LAM * (x0*M02 + x1*M12 + x2*M22 + u2);
        a2[r][0] = (v2f){av0, av0};
        a2[r][1] = (v2f){av1, av1};
        a2[r][2] = (v2f){av2, av2};
    }

    // per-lane epilogue weights (lane sub<5 owns output dim sub)
    float wv0 = 0.f, wv1 = 0.f, wv2 = 0.f, bvl = 0.f;
    if (sub < DK) {
        wv0 = Wv[sub*3+0]; wv1 = Wv[sub*3+1]; wv2 = Wv[sub*3+2]; bvl = bv[sub];
    }

    v2f l2[4];
    v2f acc2[4][4];              // {p*x0, p*x1, p*x2, p} over past keys
#pragma unroll
    for (int r = 0; r < 4; ++r) {
        l2[r] = (v2f){0.f, 0.f};
#pragma unroll
        for (int d = 0; d < 4; ++d) acc2[r][d] = (v2f){0.f, 0.f};
    }

    for (int t = 0; t < SS; t += TK) {     // 2 tiles
        __syncthreads();
        // stage AoS tile: 2048 keys x 3 floats = 1536 float4 slots, linear
#pragma unroll
        for (int it = 0; it < 6; ++it) {
            int idx = it * NT + tid;
            GLOAD16(xb + (size_t)t * 3 + idx * 4, &kls[idx * 4]);
        }
        __syncthreads();

#pragma unroll
        for (int j = 0; j < TK / 256; ++j) {   // 8 chunks of 256 keys
            const int off    = (j * 256 + sub * 4) * 3;
            const int cstart = t + j * 256;     // wave-uniform chunk bounds
            const int cend   = cstart + 255;
            const int kbase  = cstart + sub * 4;

            float4 f0 = *(const float4*)&kls[off + 0];
            float4 f1 = *(const float4*)&kls[off + 4];
            float4 f2 = *(const float4*)&kls[off + 8];

            // ---- pair loop: pp=0 -> rows lo0,lo0+1 ; pp=1 -> hi0,hi0+1 ----
#pragma unroll
            for (int pp = 0; pp < 2; ++pp) {
                const int base = pp ? hi0 : lo0;
                const int r0 = pp * 2;

                if (cend <= base) {
                    // ---- full past for this pair ----
#pragma unroll
                    for (int h = 0; h < 2; ++h) {
                        K_SLICES(h)
#pragma unroll
                        for (int rr = 0; rr < 2; ++rr) {
                            const int r = r0 + rr;
                            v2f sc = pk_fma(a2[r][0], k0,
                                     pk_fma(a2[r][1], k1, a2[r][2] * k2));
                            v2f p;
                            p.x = fast_exp2(sc.x); p.y = fast_exp2(sc.y);
                            l2[r] += p;
                            acc2[r][0] = pk_fma(p, k0, acc2[r][0]);
                            acc2[r][1] = pk_fma(p, k1, acc2[r][1]);
                            acc2[r][2] = pk_fma(p, k2, acc2[r][2]);
                            acc2[r][3] += p;
                        }
                    }
                } else if (cstart > base + 1) {
                    // ---- all future: denominator only ----
#pragma unroll
                    for (int h = 0; h < 2; ++h) {
                        K_SLICES(h)
#pragma unroll
                        for (int rr = 0; rr < 2; ++rr) {
                            const int r = r0 + rr;
                            v2f sc = pk_fma(a2[r][0], k0,
                                     pk_fma(a2[r][1], k1, a2[r][2] * k2));
                            v2f p;
                            p.x = fast_exp2(sc.x); p.y = fast_exp2(sc.y);
                            l2[r] += p;
                        }
                    }
                } else {
                    // ---- boundary chunk for this pair: masked ----
#pragma unroll
                    for (int h = 0; h < 2; ++h) {
                        const int kgh = kbase + h * 2;
                        K_SLICES(h)
#pragma unroll
                        for (int rr = 0; rr < 2; ++rr) {
                            const int r = r0 + rr;
                            const int row = base + rr;
                            v2f sc = pk_fma(a2[r][0], k0,
                                     pk_fma(a2[r][1], k1, a2[r][2] * k2));
                            v2f p;
                            p.x = fast_exp2(sc.x); p.y = fast_exp2(sc.y);
                            l2[r] += p;
                            v2f pm;
                            pm.x = (kgh + 0 <= row) ? p.x : 0.f;
                            pm.y = (kgh + 1 <= row) ? p.y : 0.f;
                            acc2[r][0] = pk_fma(pm, k0, acc2[r][0]);
                            acc2[r][1] = pk_fma(pm, k1, acc2[r][1]);
                            acc2[r][2] = pk_fma(pm, k2, acc2[r][2]);
                            acc2[r][3] += pm;
                        }
                    }
                }
            }
        }
    }

    // fold packed halves, butterfly-reduce 5 values across 64 lanes, project
#pragma unroll
    for (int r = 0; r < 4; ++r) {
        const int row = (r < 2) ? (lo0 + r) : (hi0 + r - 2);
        float lr = l2[r].x + l2[r].y;
        float A0 = acc2[r][0].x + acc2[r][0].y;
        float A1 = acc2[r][1].x + acc2[r][1].y;
        float A2 = acc2[r][2].x + acc2[r][2].y;
        float PS = acc2[r][3].x + acc2[r][3].y;
#pragma unroll
        for (int off = 32; off >= 1; off >>= 1) {
            lr += __shfl_xor(lr, off);
            A0 += __shfl_xor(A0, off);
            A1 += __shfl_xor(A1, off);
            A2 += __shfl_xor(A2, off);
            PS += __shfl_xor(PS, off);
        }
        if (sub < DK) {
            float num = fmaf(wv0, A0, fmaf(wv1, A1, fmaf(wv2, A2, bvl * PS)));
            out[((size_t)b * SS + row) * DK + sub] = num / lr;
        }
    }
}

extern "C" void kernel_launch(void* const* d_in, const int* in_sizes, int n_in,
                              void* d_out, int out_size, void* d_ws, size_t ws_size,
                              hipStream_t stream) {
    const float* x  = (const float*)d_in[0];
    const float* Wq = (const float*)d_in[1];
    const float* bq = (const float*)d_in[2];
    const float* Wk = (const float*)d_in[3];
    const float* Wv = (const float*)d_in[5];
    const float* bv = (const float*)d_in[6];
    float* outp = (float*)d_out;

    attn<<<BB * (SS / 16), NT, 0, stream>>>(x, Wq, bq, Wk, Wv, bv, outp);
}

// Round 20
// 23.491 us; speedup vs baseline: 3.5857x; 1.0091x over previous
//
#include <hip/hip_runtime.h>
#include <math.h>

#define BB 4
#define SS 4096
#define DK 5
#define TK 2048
#define NT 256
// (1/sqrt(5)) * log2(e) folded into a' so p = v_exp_f32(score)
#define LAM (0.44721359549995793f * 1.4426950408889634f)

typedef float v2f __attribute__((ext_vector_type(2)));

__device__ __forceinline__ float fast_exp2(float x) {
#if __has_builtin(__builtin_amdgcn_exp2f)
    return __builtin_amdgcn_exp2f(x);
#else
    float r; asm("v_exp_f32 %0, %1" : "=v"(r) : "v"(x)); return r;
#endif
}

// Packed fp32: compiler selects v_pk_fma_f32 on gfx90a+ for <2 x float> fma.
__device__ __forceinline__ v2f pk_fma(v2f a, v2f b, v2f c) {
    return __builtin_elementwise_fma(a, b, c);
}

// async global->LDS, 16B per lane (dest lane-contiguous)
#define GLOAD16(gp, lp)                                                        \
    __builtin_amdgcn_global_load_lds(                                          \
        (const __attribute__((address_space(1))) unsigned int*)(gp),           \
        (__attribute__((address_space(3))) unsigned int*)(lp), 16, 0, 0)

// ---------------------------------------------------------------------------
// R17 (best: 23.7 µs) with the chunk loop NOT unrolled. Theory: since R2 the
// fully-unrolled 8-chunk loop x 3-way regime branch replicated ~24 chunk
// bodies (~30-40 KB hot code) > 32 KB L1I -> I-cache thrash. Evidence: R1
// (one compact body) ran 74% VALUBusy; R2+ (replicated bodies) 36%, and all
// scheduling A/Bs since (balance R19: exact tie; occupancy R18: dead) were
// null — consistent with a front-end stall invariant to those levers.
// This build keeps ONE ~3 KB chunk body resident (runtime j), identical
// register/liveness shape otherwise.
//   score_rk = a'_r·x_k,  a'_r = LAM*(M^T x_r + Wk^T bq),  M = Wq^T Wk
//   acc_r = {Σ_past p·x, Σ_past p},  l_r = Σ_all p   (V folded out)
//   out_r,d = (Wv[d]·acc_x + bv[d]·acc_p)/l_r
// ---------------------------------------------------------------------------
__global__ __launch_bounds__(NT, 4) void attn(
    const float* __restrict__ x,
    const float* __restrict__ Wq, const float* __restrict__ bq,
    const float* __restrict__ Wk,
    const float* __restrict__ Wv, const float* __restrict__ bv,
    float* __restrict__ out)
{
    __shared__ float kls[3 * TK];          // AoS: key k at [k*3 .. k*3+2]

    const int tid = threadIdx.x;
    const int sub = tid & 63;
    const int wave = tid >> 6;

    const int b = blockIdx.x >> 8;
    const int i = blockIdx.x & 255;
    const int lowRow  = i * 8;
    const int highRow = (511 - i) * 8;
    const int row0w = (wave < 2) ? (lowRow + wave * 4) : (highRow + (wave - 2) * 4);

    // M = Wq^T Wk (3x3) and u = Wk^T bq (uniform)
    float M00=0,M01=0,M02=0,M10=0,M11=0,M12=0,M20=0,M21=0,M22=0;
    float u0=0,u1=0,u2=0;
#pragma unroll
    for (int d = 0; d < DK; ++d) {
        float q0 = Wq[d*3+0], q1 = Wq[d*3+1], q2 = Wq[d*3+2];
        float k0 = Wk[d*3+0], k1 = Wk[d*3+1], k2 = Wk[d*3+2];
        float bqd = bq[d];
        M00 = fmaf(q0,k0,M00); M01 = fmaf(q0,k1,M01); M02 = fmaf(q0,k2,M02);
        M10 = fmaf(q1,k0,M10); M11 = fmaf(q1,k1,M11); M12 = fmaf(q1,k2,M12);
        M20 = fmaf(q2,k0,M20); M21 = fmaf(q2,k1,M21); M22 = fmaf(q2,k2,M22);
        u0 = fmaf(k0,bqd,u0);  u1 = fmaf(k1,bqd,u1);  u2 = fmaf(k2,bqd,u2);
    }

    const float* xb = x + (size_t)b * SS * 3;

    // per-row a' (broadcast into both packed halves)
    v2f a2[4][3];
#pragma unroll
    for (int r = 0; r < 4; ++r) {
        const float* xr = &xb[(size_t)(row0w + r) * 3];
        float x0 = xr[0], x1 = xr[1], x2 = xr[2];
        float av0 = LAM * (x0*M00 + x1*M10 + x2*M20 + u0);
        float av1 = LAM * (x0*M01 + x1*M11 + x2*M21 + u1);
        float av2 = LAM * (x0*M02 + x1*M12 + x2*M22 + u2);
        a2[r][0] = (v2f){av0, av0};
        a2[r][1] = (v2f){av1, av1};
        a2[r][2] = (v2f){av2, av2};
    }

    // per-lane epilogue weights (lane sub<5 owns output dim sub)
    float wv0 = 0.f, wv1 = 0.f, wv2 = 0.f, bvl = 0.f;
    if (sub < DK) {
        wv0 = Wv[sub*3+0]; wv1 = Wv[sub*3+1]; wv2 = Wv[sub*3+2]; bvl = bv[sub];
    }

    v2f l2[4];
    v2f acc2[4][4];              // {p*x0, p*x1, p*x2, p} over past keys
#pragma unroll
    for (int r = 0; r < 4; ++r) {
        l2[r] = (v2f){0.f, 0.f};
#pragma unroll
        for (int d = 0; d < 4; ++d) acc2[r][d] = (v2f){0.f, 0.f};
    }

    for (int t = 0; t < SS; t += TK) {     // 2 tiles
        __syncthreads();
        // stage AoS tile: 2048 keys x 3 floats = 1536 float4 slots, linear
#pragma unroll
        for (int it = 0; it < 6; ++it) {
            int idx = it * NT + tid;
            GLOAD16(xb + (size_t)t * 3 + idx * 4, &kls[idx * 4]);
        }
        __syncthreads();

#pragma unroll 1                           // ONE chunk body in I-cache
        for (int j = 0; j < TK / 256; ++j) {   // 8 chunks of 256 keys
            const int off    = (j * 256 + sub * 4) * 3;
            const int cstart = t + j * 256;     // wave-uniform chunk bounds
            const int cend   = cstart + 255;
            const int kbase  = cstart + sub * 4;

            float4 f0 = *(const float4*)&kls[off + 0];
            float4 f1 = *(const float4*)&kls[off + 4];
            float4 f2 = *(const float4*)&kls[off + 8];

            if (cend <= row0w) {
                // ---- full past for all 4 rows ----
#pragma unroll
                for (int h = 0; h < 2; ++h) {
                    v2f k0, k1, k2;
                    if (h == 0) {
                        k0 = (v2f){f0.x, f0.w};
                        k1 = (v2f){f0.y, f1.x};
                        k2 = (v2f){f0.z, f1.y};
                    } else {
                        k0 = (v2f){f1.z, f2.y};
                        k1 = (v2f){f1.w, f2.z};
                        k2 = (v2f){f2.x, f2.w};
                    }
#pragma unroll
                    for (int r = 0; r < 4; ++r) {
                        v2f sc = pk_fma(a2[r][0], k0,
                                 pk_fma(a2[r][1], k1, a2[r][2] * k2));
                        v2f p;
                        p.x = fast_exp2(sc.x); p.y = fast_exp2(sc.y);
                        l2[r] += p;
                        acc2[r][0] = pk_fma(p, k0, acc2[r][0]);
                        acc2[r][1] = pk_fma(p, k1, acc2[r][1]);
                        acc2[r][2] = pk_fma(p, k2, acc2[r][2]);
                        acc2[r][3] += p;
                    }
                }
            } else if (cstart > row0w + 3) {
                // ---- all future: denominator only ----
#pragma unroll
                for (int h = 0; h < 2; ++h) {
                    v2f k0, k1, k2;
                    if (h == 0) {
                        k0 = (v2f){f0.x, f0.w};
                        k1 = (v2f){f0.y, f1.x};
                        k2 = (v2f){f0.z, f1.y};
                    } else {
                        k0 = (v2f){f1.z, f2.y};
                        k1 = (v2f){f1.w, f2.z};
                        k2 = (v2f){f2.x, f2.w};
                    }
#pragma unroll
                    for (int r = 0; r < 4; ++r) {
                        v2f sc = pk_fma(a2[r][0], k0,
                                 pk_fma(a2[r][1], k1, a2[r][2] * k2));
                        v2f p;
                        p.x = fast_exp2(sc.x); p.y = fast_exp2(sc.y);
                        l2[r] += p;
                    }
                }
            } else {
                // ---- boundary chunk (exactly one per wave) ----
#pragma unroll
                for (int h = 0; h < 2; ++h) {
                    const int kgh = kbase + h * 2;
                    v2f k0, k1, k2;
                    if (h == 0) {
                        k0 = (v2f){f0.x, f0.w};
                        k1 = (v2f){f0.y, f1.x};
                        k2 = (v2f){f0.z, f1.y};
                    } else {
                        k0 = (v2f){f1.z, f2.y};
                        k1 = (v2f){f1.w, f2.z};
                        k2 = (v2f){f2.x, f2.w};
                    }
#pragma unroll
                    for (int r = 0; r < 4; ++r) {
                        const int row = row0w + r;
                        v2f sc = pk_fma(a2[r][0], k0,
                                 pk_fma(a2[r][1], k1, a2[r][2] * k2));
                        v2f p;
                        p.x = fast_exp2(sc.x); p.y = fast_exp2(sc.y);
                        l2[r] += p;
                        v2f pm;
                        pm.x = (kgh + 0 <= row) ? p.x : 0.f;
                        pm.y = (kgh + 1 <= row) ? p.y : 0.f;
                        acc2[r][0] = pk_fma(pm, k0, acc2[r][0]);
                        acc2[r][1] = pk_fma(pm, k1, acc2[r][1]);
                        acc2[r][2] = pk_fma(pm, k2, acc2[r][2]);
                        acc2[r][3] += pm;
                    }
                }
            }
        }
    }

    // fold packed halves, butterfly-reduce 5 values across 64 lanes, project
#pragma unroll
    for (int r = 0; r < 4; ++r) {
        float lr = l2[r].x + l2[r].y;
        float A0 = acc2[r][0].x + acc2[r][0].y;
        float A1 = acc2[r][1].x + acc2[r][1].y;
        float A2 = acc2[r][2].x + acc2[r][2].y;
        float PS = acc2[r][3].x + acc2[r][3].y;
#pragma unroll
        for (int off = 32; off >= 1; off >>= 1) {
            lr += __shfl_xor(lr, off);
            A0 += __shfl_xor(A0, off);
            A1 += __shfl_xor(A1, off);
            A2 += __shfl_xor(A2, off);
            PS += __shfl_xor(PS, off);
        }
        if (sub < DK) {
            float num = fmaf(wv0, A0, fmaf(wv1, A1, fmaf(wv2, A2, bvl * PS)));
            out[((size_t)b * SS + row0w + r) * DK + sub] = num / lr;
        }
    }
}

extern "C" void kernel_launch(void* const* d_in, const int* in_sizes, int n_in,
                              void* d_out, int out_size, void* d_ws, size_t ws_size,
                              hipStream_t stream) {
    const float* x  = (const float*)d_in[0];
    const float* Wq = (const float*)d_in[1];
    const float* bq = (const float*)d_in[2];
    const float* Wk = (const float*)d_in[3];
    const float* Wv = (const float*)d_in[5];
    const float* bv = (const float*)d_in[6];
    float* outp = (float*)d_out;

    attn<<<BB * (SS / 16), NT, 0, stream>>>(x, Wq, bq, Wk, Wv, bv, outp);
}